// Round 8
// baseline (244.633 us; speedup 1.0000x reference)
//
#include <hip/hip_runtime.h>

#define BB 8
#define NN 6
#define DD 45
#define CC 64
#define FHH 8
#define FWW 22
#define GXX 64
#define GYY 64
#define GZZ 32
#define NPOINTS (BB*NN*DD*FHH*FWW)       // 380160 = 1485*256
#define NSITES (BB*NN*FHH*FWW)           // 8448
#define NFEATT (NSITES*CC)               // 540672 = 2112*256
#define ROWS (BB*GZZ)                    // 256 (b,nz) rows
#define CAPR 8192                        // worst row ~3500 entries -> 2.3x margin

typedef float f32x4 __attribute__((ext_vector_type(4)));

// ws layout (bytes): cnt[ROWS] | bucket2[ROWS*CAPR] (int2) | featC[C][NSITES]
#define WS_CNT_OFF 0
#define WS_BUCKET_OFF 1024
#define WS_FEATC_OFF (WS_BUCKET_OFF + (size_t)ROWS * CAPR * 8)
#define WS_NEEDED (WS_FEATC_OFF + (size_t)NFEATT * 4)

__global__ __launch_bounds__(256) void lss_zero(float4* __restrict__ p, int n4) {
    int i = blockIdx.x * blockDim.x + threadIdx.x;
    int stride = gridDim.x * blockDim.x;
    float4 z = make_float4(0.f, 0.f, 0.f, 0.f);
    for (; i < n4; i += stride) p[i] = z;
}

// feature [B,N,C,FH,FW] -> featC [C][site]  (site = (cam*FH+h)*FW+w, cam = b*N+n)
// Each block's (uniform-c) scan slice is then 33KB -> L1-resident. Also zeroes cnt[].
__global__ __launch_bounds__(256) void lss_featC(const float* __restrict__ feature,
                                                 float* __restrict__ featC,
                                                 int* __restrict__ cnt) {
    int idx = blockIdx.x * 256 + threadIdx.x;        // < NFEATT
    if (idx < ROWS) cnt[idx] = 0;
    int site = idx % NSITES;
    int c = idx / NSITES;
    int hw = site % (FHH * FWW);
    int cam = site / (FHH * FWW);
    featC[idx] = feature[(cam * CC + c) * (FHH * FWW) + hw];
}

// Per-point geometry -> (row=(b,nz), dv, site, nx, ny); append to row bucket.
// Wave-aggregated rank atomics; depth is premultiplied into the entry.
__global__ __launch_bounds__(256) void lss_build(
    const float* __restrict__ depth,
    const float* __restrict__ rots, const float* __restrict__ trans,
    const float* __restrict__ intr,
    int* __restrict__ cnt, int2* __restrict__ bucket2)
{
    int p = blockIdx.x * 256 + threadIdx.x;          // < NPOINTS
    int lane = threadIdx.x & 63;
    int w = p % FWW;
    int t = p / FWW;
    int h = t % FHH; t /= FHH;
    int di = t % DD; t /= DD;
    int n = t % NN;
    int b = t / NN;

    float d = (float)(di + 1);
    float x = (float)(351.0 * (double)w / 21.0);
    float y = (float)(127.0 * (double)h / 7.0);

    const float* K = intr + (b * NN + n) * 9;
    double k00 = K[0], k01 = K[1], k02 = K[2];
    double k10 = K[3], k11 = K[4], k12 = K[5];
    double k20 = K[6], k21 = K[7], k22 = K[8];
    double det = k00 * (k11 * k22 - k12 * k21)
               - k01 * (k10 * k22 - k12 * k20)
               + k02 * (k10 * k21 - k11 * k20);
    double id = 1.0 / det;
    float i00 = (float)(( k11 * k22 - k12 * k21) * id);
    float i01 = (float)((-k01 * k22 + k02 * k21) * id);
    float i02 = (float)(( k01 * k12 - k02 * k11) * id);
    float i10 = (float)((-k10 * k22 + k12 * k20) * id);
    float i11 = (float)(( k00 * k22 - k02 * k20) * id);
    float i12 = (float)((-k00 * k12 + k02 * k10) * id);
    float i20 = (float)(( k10 * k21 - k11 * k20) * id);
    float i21 = (float)((-k00 * k21 + k01 * k20) * id);
    float i22 = (float)(( k00 * k11 - k01 * k10) * id);

    float p0 = x * d, p1 = y * d, p2 = d;
    float c0 = i00 * p0 + i01 * p1 + i02 * p2;
    float c1 = i10 * p0 + i11 * p1 + i12 * p2;
    float c2 = i20 * p0 + i21 * p1 + i22 * p2;

    const float* R = rots + (b * NN + n) * 9;
    const float* T = trans + (b * NN + n) * 3;
    float g0 = R[0] * c0 + R[1] * c1 + R[2] * c2 + T[0];
    float g1 = R[3] * c0 + R[4] * c1 + R[5] * c2 + T[1];
    float g2 = R[6] * c0 + R[7] * c1 + R[8] * c2 + T[2];

    int nx = (int)((g0 + 16.0f) / 0.5f);
    int ny = (int)((g2 + 16.0f) / 0.5f);
    int nz = (int)((g1 + 8.0f)  / 0.5f);
    bool valid = (nx >= 0) & (nx < GXX) & (ny >= 0) & (ny < GYY) & (nz >= 0) & (nz < GZZ);

    int row = valid ? (b * GZZ + nz) : -1;
    int site = (((b * NN + n) * FHH) + h) * FWW + w;
    int meta = (site << 12) | (nx << 6) | ny;        // site<8448 (14b) | nx(6b) | ny(6b)
    float dv = depth[p];                              // coalesced (depth layout == p order)

    unsigned long long active = __ballot(valid);
    while (active) {
        int leader = __ffsll((unsigned long long)active) - 1;
        int lrow = __shfl(row, leader);
        unsigned long long same = __ballot(valid && (row == lrow));
        int base = 0;
        if (lane == leader) base = atomicAdd(&cnt[lrow], (int)__popcll(same));
        base = __shfl(base, leader);
        if (valid && (row == lrow)) {
            int off = (int)__popcll(same & ((1ull << lane) - 1ull));
            int rank = base + off;
            if (rank < CAPR) bucket2[lrow * CAPR + rank] = make_int2(__float_as_int(dv), meta);
        }
        active &= ~same;
    }
}

// One block per OUTPUT PLANE bid = (b*CC + c)*GZZ + nz  (16384 planes, 16KB each).
// 16KB LDS -> 8 blocks/CU; concurrent blocks write sequential planes; featC slice
// for uniform c is 33KB (L1-resident). Nontemporal stores (write-once output).
__global__ __launch_bounds__(256) void lss_out5(
    const float* __restrict__ featC,
    const int* __restrict__ cnt, const int2* __restrict__ bucket2,
    float* __restrict__ out)
{
    int bid = blockIdx.x;
    int nz = bid & 31;
    int c  = (bid >> 5) & 63;
    int b  = bid >> 11;
    int row = (b << 5) | nz;
    int tid = threadIdx.x;

    int scnt = cnt[row];
    if (scnt > CAPR) scnt = CAPR;

    f32x4* oplane = (f32x4*)(out + (size_t)bid * (GXX * GYY));

    if (scnt == 0) {
        f32x4 z = (f32x4){0.f, 0.f, 0.f, 0.f};
        #pragma unroll
        for (int k = 0; k < 4; ++k)
            __builtin_nontemporal_store(z, oplane + tid + k * 256);
        return;
    }

    __shared__ float acc[GXX * GYY];       // 16 KB
    f32x4* a4 = (f32x4*)acc;
    {
        f32x4 z = (f32x4){0.f, 0.f, 0.f, 0.f};
        #pragma unroll
        for (int k = 0; k < 4; ++k) a4[tid + k * 256] = z;
    }
    __syncthreads();

    const float* fslice = featC + (size_t)c * NSITES;   // 33KB, L1-resident
    const int2* bk = bucket2 + (size_t)row * CAPR;
    for (int e = tid; e < scnt; e += 256) {
        int2 en = bk[e];
        float dv = __int_as_float(en.x);
        int meta = en.y;
        int site = meta >> 12;
        int nxny = meta & 4095;            // (nx<<6)|ny
        atomicAdd(&acc[nxny], dv * fslice[site]);
    }
    __syncthreads();

    #pragma unroll
    for (int k = 0; k < 4; ++k)
        __builtin_nontemporal_store(a4[tid + k * 256], oplane + tid + k * 256);
}

// ---- fallback (R1 path) ----
__global__ __launch_bounds__(256) void lss_scatter_direct(
    const float* __restrict__ depth, const float* __restrict__ feature,
    const float* __restrict__ rots, const float* __restrict__ trans,
    const float* __restrict__ intr, float* __restrict__ out)
{
    int p = blockIdx.x * 4 + (threadIdx.x >> 6);
    int lane = threadIdx.x & 63;
    int w = p % FWW;
    int t = p / FWW;
    int h = t % FHH; t /= FHH;
    int di = t % DD; t /= DD;
    int n = t % NN;
    int b = t / NN;
    float d = (float)(di + 1);
    float x = (float)(351.0 * (double)w / 21.0);
    float y = (float)(127.0 * (double)h / 7.0);
    const float* K = intr + (b * NN + n) * 9;
    double k00 = K[0], k01 = K[1], k02 = K[2];
    double k10 = K[3], k11 = K[4], k12 = K[5];
    double k20 = K[6], k21 = K[7], k22 = K[8];
    double det = k00*(k11*k22-k12*k21) - k01*(k10*k22-k12*k20) + k02*(k10*k21-k11*k20);
    double id = 1.0 / det;
    float i00=(float)((k11*k22-k12*k21)*id), i01=(float)((-k01*k22+k02*k21)*id), i02=(float)((k01*k12-k02*k11)*id);
    float i10=(float)((-k10*k22+k12*k20)*id), i11=(float)((k00*k22-k02*k20)*id), i12=(float)((-k00*k12+k02*k10)*id);
    float i20=(float)((k10*k21-k11*k20)*id), i21=(float)((-k00*k21+k01*k20)*id), i22=(float)((k00*k11-k01*k10)*id);
    float p0 = x * d, p1 = y * d, p2 = d;
    float c0 = i00*p0 + i01*p1 + i02*p2;
    float c1 = i10*p0 + i11*p1 + i12*p2;
    float c2 = i20*p0 + i21*p1 + i22*p2;
    const float* R = rots + (b * NN + n) * 9;
    const float* T = trans + (b * NN + n) * 3;
    float g0 = R[0]*c0 + R[1]*c1 + R[2]*c2 + T[0];
    float g1 = R[3]*c0 + R[4]*c1 + R[5]*c2 + T[1];
    float g2 = R[6]*c0 + R[7]*c1 + R[8]*c2 + T[2];
    int nx = (int)((g0 + 16.0f) / 0.5f);
    int ny = (int)((g2 + 16.0f) / 0.5f);
    int nz = (int)((g1 + 8.0f)  / 0.5f);
    if (!((nx >= 0) & (nx < GXX) & (ny >= 0) & (ny < GYY) & (nz >= 0) & (nz < GZZ)))
        return;
    float dv = depth[(((b * NN + n) * DD + di) * FHH + h) * FWW + w];
    float fv = feature[(((b * NN + n) * CC + lane) * FHH + h) * FWW + w];
    size_t oidx = ((((size_t)b * CC + lane) * GZZ + nz) * GXX + nx) * GYY + ny;
    atomicAdd(out + oidx, dv * fv);
}

extern "C" void kernel_launch(void* const* d_in, const int* in_sizes, int n_in,
                              void* d_out, int out_size, void* d_ws, size_t ws_size,
                              hipStream_t stream) {
    const float* depth   = (const float*)d_in[0];
    const float* feature = (const float*)d_in[1];
    const float* rots    = (const float*)d_in[2];
    const float* trans   = (const float*)d_in[3];
    const float* intr    = (const float*)d_in[4];
    float* out = (float*)d_out;

    if (ws_size >= WS_NEEDED) {
        int*   cnt     = (int*)((char*)d_ws + WS_CNT_OFF);
        int2*  bucket2 = (int2*)((char*)d_ws + WS_BUCKET_OFF);
        float* featC   = (float*)((char*)d_ws + WS_FEATC_OFF);

        // 1) feat transpose to [C][site] + zero row counts
        lss_featC<<<NFEATT / 256, 256, 0, stream>>>(feature, featC, cnt);
        // 2) build per-(b,nz)-row buckets (depth premultiplied into entries)
        lss_build<<<NPOINTS / 256, 256, 0, stream>>>(depth, rots, trans, intr, cnt, bucket2);
        // 3) one block per output plane: 16KB LDS, 8 blocks/CU, sequential nt-stores
        lss_out5<<<BB * CC * GZZ, 256, 0, stream>>>(featC, cnt, bucket2, out);
    } else {
        lss_zero<<<4096, 256, 0, stream>>>((float4*)out, out_size / 4);
        lss_scatter_direct<<<NPOINTS / 4, 256, 0, stream>>>(depth, feature, rots, trans, intr, out);
    }
}